// Round 9
// baseline (250.596 us; speedup 1.0000x reference)
//
#include <hip/hip_runtime.h>
#include <stdint.h>

// Problem constants
#define B_SZ   8192
#define IN_DIM 320      // S + A
#define H_DIM  1024
#define E_NUM  8
#define OUT_DIM 257     // S + 1
#define MAXT2  136      // TM=64 tile table  (8192/64 + 8 experts)
#define MAXT3  40       // TM=256 tile table (8192/256 + 8 experts)

typedef __bf16 bf16x8 __attribute__((ext_vector_type(8)));
typedef float  f32x4  __attribute__((ext_vector_type(4)));

typedef unsigned int __attribute__((address_space(1))) as1_uint;
typedef unsigned int __attribute__((address_space(3))) as3_uint;

__device__ __forceinline__ void gload_lds16(const void* g, void* l) {
    // async global->LDS, 16B/lane; LDS dest is wave-uniform base + lane*16
    __builtin_amdgcn_global_load_lds((const as1_uint*)g, (as3_uint*)l, 16, 0, 0);
}

__device__ __forceinline__ unsigned short f2bf(float f) {
    unsigned int u = __float_as_uint(f);
    return (unsigned short)((u + 0x7fffu + ((u >> 16) & 1u)) >> 16);  // RNE
}

// ---------------------------------------------------------------------------
// Transpose-convert nkt 64x64 tiles (verified R1/R7 body, NT-thread variant):
// float4 global loads -> bf16 -> padded LDS (stride 65) -> ushort4 stores.
template <int NT>
__device__ __forceinline__ void transpose_tiles(
    char* smem, int e, int nt, int kt0, int nkt,
    int K, int Nsrc, int dstRows, bool vec,
    const float* __restrict__ src, unsigned short* __restrict__ dst) {
    unsigned short (*tileU)[65] = (unsigned short(*)[65])smem;
    constexpr int RP = NT / 16;   // rows per pass
    constexpr int NP = 64 / RP;   // passes
    int tid = threadIdx.x;
    const float* s = src + (size_t)e * K * Nsrc;
    unsigned short* d = dst + (size_t)e * dstRows * K;
    int c4 = (tid & 15) * 4;
    int rb = tid >> 4;
    int n0 = nt * 64;
    for (int kt = kt0; kt < kt0 + nkt; kt++) {
        int k0 = kt * 64;
#pragma unroll
        for (int p = 0; p < NP; p++) {
            int r = rb + p * RP;
            const float* sp = s + (size_t)(k0 + r) * Nsrc + n0 + c4;
            float4 v;
            if (vec) v = *(const float4*)sp;
            else { v.x = sp[0]; v.y = sp[1]; v.z = sp[2]; v.w = sp[3]; }
            tileU[r][c4 + 0] = f2bf(v.x);
            tileU[r][c4 + 1] = f2bf(v.y);
            tileU[r][c4 + 2] = f2bf(v.z);
            tileU[r][c4 + 3] = f2bf(v.w);
        }
        __syncthreads();
#pragma unroll
        for (int p = 0; p < NP; p++) {
            int n = rb + p * RP;
            ushort4 o;
            o.x = tileU[c4 + 0][n];
            o.y = tileU[c4 + 1][n];
            o.z = tileU[c4 + 2][n];
            o.w = tileU[c4 + 3][n];
            *(ushort4*)&d[(size_t)(n0 + n) * K + k0 + c4] = o;
        }
        __syncthreads();             // tileU reused next kt
    }
}

// ---------------------------------------------------------------------------
// Bucket rows by expert + build TM=64 and TM=256 tile tables.
__device__ __forceinline__ void prep_bucket(
    char* smem, const int* __restrict__ idx, int* __restrict__ order,
    int* __restrict__ te2, int* __restrict__ tp2, int* __restrict__ tc2,
    int* __restrict__ te3, int* __restrict__ tp3, int* __restrict__ tc3) {
    int (*scnt)[E_NUM] = (int(*)[E_NUM])smem;
    int tid = threadIdx.x;
    int shard = tid & 15;
    if (tid < 128) ((int*)scnt)[tid] = 0;
    __syncthreads();
    for (int b = tid; b < B_SZ; b += 256) atomicAdd(&scnt[shard][idx[b]], 1);
    __syncthreads();
    if (tid == 0) {
        int pos = 0, t2 = 0, t3 = 0;
        for (int e = 0; e < E_NUM; e++) {
            int start = pos;
            for (int s = 0; s < 16; s++) { int c = scnt[s][e]; scnt[s][e] = pos; pos += c; }
            int tot = pos - start;
            for (int st = 0; st < tot; st += 64) {
                te2[t2] = e; tp2[t2] = start + st; tc2[t2] = min(64, tot - st); t2++;
            }
            for (int st = 0; st < tot; st += 256) {
                te3[t3] = e; tp3[t3] = start + st; tc3[t3] = min(256, tot - st); t3++;
            }
        }
        for (; t2 < MAXT2; t2++) { te2[t2] = 0; tp2[t2] = 0; tc2[t2] = 0; }
        for (; t3 < MAXT3; t3++) { te3[t3] = 0; tp3[t3] = 0; tc3[t3] = 0; }
    }
    __syncthreads();
    for (int b = tid; b < B_SZ; b += 256) {
        int e = idx[b];
        int p = atomicAdd(&scnt[shard][e], 1);
        order[p] = b;
    }
}

// ---------------------------------------------------------------------------
// Dispatch 1 (256 thr): bucket+tables (bid 0) | x-concat (1..320) |
// W1 transpose (321..960). Verified R7 structure.
__global__ __launch_bounds__(256)
void k_prepA(const float* __restrict__ state, const float* __restrict__ action,
             const int* __restrict__ idx, const float* __restrict__ W1,
             unsigned short* __restrict__ xb, unsigned short* __restrict__ w1t,
             int* __restrict__ order,
             int* __restrict__ te2, int* __restrict__ tp2, int* __restrict__ tc2,
             int* __restrict__ te3, int* __restrict__ tp3, int* __restrict__ tc3) {
    __shared__ __align__(16) char smem[8448];
    int bid = blockIdx.x, tid = threadIdx.x;

    if (bid == 0) {
        prep_bucket(smem, idx, order, te2, tp2, tc2, te3, tp3, tc3);
        return;
    }
    if (bid <= 320) {
#pragma unroll
        for (int k = 0; k < 8; k++) {
            int q = ((bid - 1) * 8 + k) * 256 + tid;   // quad id: b*80 + j
            int b = q / 80, j = q % 80;
            float4 v = (j < 64) ? ((const float4*)state)[b * 64 + j]
                                : ((const float4*)action)[b * 16 + (j - 64)];
            ushort4 o;
            o.x = f2bf(v.x); o.y = f2bf(v.y); o.z = f2bf(v.z); o.w = f2bf(v.w);
            ((ushort4*)xb)[q] = o;
        }
        return;
    }
    // W1: (8,320,1024) -> (8,1024,320); 640 tiles, 1 per block
    int r = bid - 321;
    int e = r / 80, m = r % 80;
    transpose_tiles<256>(smem, e, m % 16, m / 16, 1, IN_DIM, H_DIM, H_DIM, true, W1, w1t);
}

// ---------------------------------------------------------------------------
// 256x256 grouped-GEMM tile, 512 threads (8 waves, 2x4 grid; wave = 128x64,
// acc[8][4]). Same proven 2-stage dbuf + XOR-swizzle K-loop as the 128x128
// kernel — only geometry scaled: per K-step 32 MFMA + 12 ds_read_b128 +
// 4 global_load_lds_dwordx4; staged bytes per output element HALVED
// (the measured L3-fabric bottleneck). LDS 64KB.
// MODE 0 epilogue: Hout = bf16(relu(acc + bias)).
template <int K, bool GATHER>
__device__ __forceinline__ void gemm256_tile(
    char* lds, int t, int ny,
    const unsigned short* __restrict__ Abase,
    const unsigned short* __restrict__ Wt,
    const float* __restrict__ bias,
    unsigned short* __restrict__ Hout,
    const int* __restrict__ order,
    const int* __restrict__ te, const int* __restrict__ tp0,
    const int* __restrict__ tcnt) {
    constexpr int NI  = K / 32;
    constexpr int ABY = 256 * 64;         // 16KB
    constexpr int STG = 2 * ABY;          // 32KB per stage (A+B)

    int cnt = tcnt[t];
    if (cnt == 0) return;
    int e = te[t], p0 = tp0[t];
    int n0 = ny * 256;
    int tid = threadIdx.x;
    int w = tid >> 6, lane = tid & 63;
    int wm = w >> 2, wn = w & 3;          // 2x4 wave grid

    // staging: thread (r0 = tid>>2 in 0..127, c = tid&3) fills rows r0 and
    // r0+128 of A and B; fetches global chunk c ^ ((r0>>1)&3).
    // ((r0+128)>>1)&3 == (r0>>1)&3, so cg2 shared.
    int r0 = tid >> 2;
    int cg2 = (tid & 3) ^ ((r0 >> 1) & 3);
    int rc0 = r0 < cnt ? r0 : cnt - 1;
    int rc1 = (r0 + 128) < cnt ? (r0 + 128) : cnt - 1;
    long a0 = GATHER ? order[p0 + rc0] : (p0 + rc0);
    long a1 = GATHER ? order[p0 + rc1] : (p0 + rc1);
    const unsigned short* aP0 = Abase + (size_t)a0 * K + cg2 * 8;
    const unsigned short* aP1 = Abase + (size_t)a1 * K + cg2 * 8;
    const unsigned short* bP0 = Wt + ((size_t)e * H_DIM + n0 + r0) * K + cg2 * 8;
    const unsigned short* bP1 = bP0 + (size_t)128 * K;

    auto stage = [&](int k0s, int sb) {
        gload_lds16(aP0 + k0s, lds + sb + tid * 16);
        gload_lds16(aP1 + k0s, lds + sb + 8192 + tid * 16);
        gload_lds16(bP0 + k0s, lds + sb + ABY + tid * 16);
        gload_lds16(bP1 + k0s, lds + sb + ABY + 8192 + tid * 16);
    };

    f32x4 acc[8][4];
#pragma unroll
    for (int i = 0; i < 8; i++)
#pragma unroll
        for (int j = 0; j < 4; j++) acc[i][j] = (f32x4)0.f;

    const int fm   = lane & 15;
    const int kc   = lane >> 4;
    const int koff = ((kc ^ ((fm >> 1) & 3)) * 8);  // swizzled k-chunk offset

    stage(0, 0);
    for (int it = 0; it < NI; ++it) {
        __syncthreads();                 // drains tile-it loads (issued 1 iter ago)
        if (it + 1 < NI) stage((it + 1) * 32, ((it + 1) & 1) * STG);
        const unsigned short* Ls = (const unsigned short*)(lds + (it & 1) * STG);
        const unsigned short* As = Ls + wm * 128 * 32;          // wave's 128-row A half
        const unsigned short* Bs = Ls + ABY / 2 + wn * 64 * 32; // wave's 64-col B slice

        bf16x8 af[8], bf[4];
#pragma unroll
        for (int i = 0; i < 8; i++)
            af[i] = *(const bf16x8*)&As[(i * 16 + fm) * 32 + koff];
#pragma unroll
        for (int j = 0; j < 4; j++)
            bf[j] = *(const bf16x8*)&Bs[(j * 16 + fm) * 32 + koff];
#pragma unroll
        for (int i = 0; i < 8; i++)
#pragma unroll
            for (int j = 0; j < 4; j++)
                acc[i][j] = __builtin_amdgcn_mfma_f32_16x16x32_bf16(
                    af[i], bf[j], acc[i][j], 0, 0, 0);
    }

    // epilogue: C/D mapping col = lane&15, row = (lane>>4)*4 + reg
    int col = lane & 15, rq = lane >> 4;
#pragma unroll
    for (int j = 0; j < 4; j++) {
        int n = n0 + wn * 64 + j * 16 + col;
        float bv = bias[e * H_DIM + n];
#pragma unroll
        for (int i = 0; i < 8; i++) {
#pragma unroll
            for (int rr = 0; rr < 4; rr++) {
                int m = wm * 128 + i * 16 + rq * 4 + rr;
                if (m < cnt) {
                    float v = acc[i][j][rr] + bv;
                    Hout[(size_t)(p0 + m) * H_DIM + n] = f2bf(fmaxf(v, 0.f));
                }
            }
        }
    }
}

// ---------------------------------------------------------------------------
// Dispatch 2 (512 thr, 720 blocks): L1 256x256 GEMM (bid 0..159; only 160 of
// 256 CUs) + W2 transpose (160..671) + W3 transpose (672..703) + W3 reward
// column (704..719) on the idle CUs. R7's co-schedule failed with ZERO idle
// CUs; here the GEMM under-fills by design.
__global__ __launch_bounds__(512, 1)
void k_mix1(const unsigned short* __restrict__ xb,
            const unsigned short* __restrict__ w1t,
            const float* __restrict__ b1, unsigned short* __restrict__ h1,
            const int* __restrict__ order,
            const int* __restrict__ te3, const int* __restrict__ tp3,
            const int* __restrict__ tc3,
            const float* __restrict__ W2, unsigned short* __restrict__ w2t,
            const float* __restrict__ W3, unsigned short* __restrict__ w3t) {
    __shared__ __align__(16) char lds[65536];
    int bid = blockIdx.x;
    if (bid < 160) {
        gemm256_tile<IN_DIM, true>(lds, bid % MAXT3, bid / MAXT3,
                                   xb, w1t, b1, h1, order, te3, tp3, tc3);
    } else if (bid < 672) {
        int b = bid - 160;               // W2 (8,1024,1024)->(8,1024,1024)
        int e = b >> 6, r = b & 63;
        transpose_tiles<512>(lds, e, r >> 2, (r & 3) * 4, 4,
                             H_DIM, H_DIM, H_DIM, true, W2, w2t);
    } else if (bid < 704) {
        int b = bid - 672;               // W3 -> rows 0..255 of (8,320,1024)
        transpose_tiles<512>(lds, b >> 2, b & 3, 0, 16,
                             H_DIM, OUT_DIM, 320, false, W3, w3t);
    } else {
        int i = (bid - 704) * 512 + threadIdx.x;   // 8192 = 8e x 1024k
        int e = i >> 10, k = i & 1023;
        w3t[((size_t)e * 320 + 256) * H_DIM + k] =
            f2bf(W3[((size_t)e * H_DIM + k) * OUT_DIM + 256]);
    }
}

// ---------------------------------------------------------------------------
// Dispatch 3 (512 thr, 160 blocks): L2 256x256 GEMM. Staged bytes 144MB
// (vs 288MB at 128x128) — the L3-fabric bottleneck halved.
__global__ __launch_bounds__(512, 1)
void k_l2(const unsigned short* __restrict__ h1,
          const unsigned short* __restrict__ w2t,
          const float* __restrict__ b2, unsigned short* __restrict__ h2,
          const int* __restrict__ order,
          const int* __restrict__ te3, const int* __restrict__ tp3,
          const int* __restrict__ tc3) {
    __shared__ __align__(16) char lds[65536];
    int bid = blockIdx.x;
    gemm256_tile<H_DIM, false>(lds, bid % MAXT3, bid / MAXT3,
                               h1, w2t, b2, h2, order, te3, tp3, tc3);
}

// ---------------------------------------------------------------------------
// Dispatch 4 (256 thr): layer 3 + fused reward, R7-verified 64x64 tile body.
__global__ __launch_bounds__(256, 2)
void k_l3(const unsigned short* __restrict__ h2,
          const unsigned short* __restrict__ w3t,
          const float* __restrict__ b3,
          float* __restrict__ Out, const float* __restrict__ state,
          const int* __restrict__ order,
          const int* __restrict__ te, const int* __restrict__ tp0,
          const int* __restrict__ tcnt) {
    constexpr int K = H_DIM;
    constexpr int NI = K / 32;
    constexpr int ABY = 64 * 64;
    constexpr int STG = 2 * ABY;
    __shared__ __align__(16) char lds[2 * STG];

    int t = blockIdx.x % MAXT2, ny = blockIdx.x / MAXT2;
    int cnt = tcnt[t];
    if (cnt == 0) return;
    int e = te[t], p0 = tp0[t];
    int n0 = ny * 64;
    int tid = threadIdx.x;
    int w = tid >> 6, lane = tid & 63;
    int wm = w >> 1, wn = w & 1;

    int r0 = tid >> 2;
    int cg2 = (tid & 3) ^ ((r0 >> 1) & 3);
    int rc0 = r0 < cnt ? r0 : cnt - 1;
    const unsigned short* aP0 = h2 + (size_t)(p0 + rc0) * K + cg2 * 8;
    const unsigned short* bP0 = w3t + ((size_t)e * 320 + n0 + r0) * K + cg2 * 8;

    auto stage = [&](int k0s, int sb) {
        gload_lds16(aP0 + k0s, lds + sb + tid * 16);
        gload_lds16(bP0 + k0s, lds + sb + ABY + tid * 16);
    };

    f32x4 acc[2][2];
#pragma unroll
    for (int i = 0; i < 2; i++)
#pragma unroll
        for (int j = 0; j < 2; j++) acc[i][j] = (f32x4)0.f;

    const int fm   = lane & 15;
    const int kc   = lane >> 4;
    const int koff = ((kc ^ ((fm >> 1) & 3)) * 8);

    stage(0, 0);
    for (int it = 0; it < NI; ++it) {
        __syncthreads();
        if (it + 1 < NI) stage((it + 1) * 32, ((it + 1) & 1) * STG);
        const unsigned short* Ls = (const unsigned short*)(lds + (it & 1) * STG);
        const unsigned short* As = Ls + wm * 32 * 32;
        const unsigned short* Bs = Ls + ABY / 2 + wn * 32 * 32;

        bf16x8 af[2], bf[2];
#pragma unroll
        for (int i = 0; i < 2; i++)
            af[i] = *(const bf16x8*)&As[(i * 16 + fm) * 32 + koff];
#pragma unroll
        for (int j = 0; j < 2; j++)
            bf[j] = *(const bf16x8*)&Bs[(j * 16 + fm) * 32 + koff];
#pragma unroll
        for (int i = 0; i < 2; i++)
#pragma unroll
            for (int j = 0; j < 2; j++)
                acc[i][j] = __builtin_amdgcn_mfma_f32_16x16x32_bf16(
                    af[i], bf[j], acc[i][j], 0, 0, 0);
    }

    int col = lane & 15, rq = lane >> 4;
#pragma unroll
    for (int j = 0; j < 2; j++) {
        int n = n0 + wn * 32 + j * 16 + col;
        float bv = (n <= 256) ? b3[e * OUT_DIM + n] : 0.f;
#pragma unroll
        for (int i = 0; i < 2; i++) {
#pragma unroll
            for (int rr = 0; rr < 4; rr++) {
                int m = wm * 32 + i * 16 + rq * 4 + rr;
                if (m < cnt) {
                    float v = acc[i][j][rr] + bv;
                    int row = order[p0 + m];
                    if (n < 256) {
                        size_t o = (size_t)row * 256 + n;
                        Out[o] = state[o] + v;
                    } else if (n == 256) {
                        Out[(size_t)B_SZ * 256 + row] = v;   // reward
                    }
                }
            }
        }
    }
}

// ---------------------------------------------------------------------------
extern "C" void kernel_launch(void* const* d_in, const int* in_sizes, int n_in,
                              void* d_out, int out_size, void* d_ws, size_t ws_size,
                              hipStream_t stream) {
    const float* state  = (const float*)d_in[0];
    const float* action = (const float*)d_in[1];
    const int*   idx    = (const int*)d_in[2];
    const float* W1     = (const float*)d_in[3];
    const float* b1     = (const float*)d_in[4];
    const float* W2     = (const float*)d_in[5];
    const float* b2     = (const float*)d_in[6];
    const float* W3     = (const float*)d_in[7];
    const float* b3     = (const float*)d_in[8];
    float* out = (float*)d_out;

    char* ws = (char*)d_ws;
    size_t off = 0;
    auto alloc = [&](size_t bytes) -> void* {
        void* p = ws + off;
        off = (off + bytes + 255) & ~(size_t)255;
        return p;
    };
    unsigned short* xb  = (unsigned short*)alloc((size_t)B_SZ * IN_DIM * 2);
    unsigned short* w1t = (unsigned short*)alloc((size_t)E_NUM * H_DIM * IN_DIM * 2);
    unsigned short* w2t = (unsigned short*)alloc((size_t)E_NUM * H_DIM * H_DIM * 2);
    unsigned short* w3t = (unsigned short*)alloc((size_t)E_NUM * 320 * H_DIM * 2);
    unsigned short* h1  = (unsigned short*)alloc((size_t)B_SZ * H_DIM * 2);
    unsigned short* h2  = (unsigned short*)alloc((size_t)B_SZ * H_DIM * 2);
    int* order = (int*)alloc(B_SZ * 4);
    int* te2   = (int*)alloc(MAXT2 * 4);
    int* tp2   = (int*)alloc(MAXT2 * 4);
    int* tc2   = (int*)alloc(MAXT2 * 4);
    int* te3   = (int*)alloc(MAXT3 * 4);
    int* tp3   = (int*)alloc(MAXT3 * 4);
    int* tc3   = (int*)alloc(MAXT3 * 4);

    // dispatch 1: bucket + tables + x-concat + W1 transpose (961 blocks)
    k_prepA<<<961, 256, 0, stream>>>(state, action, idx, W1, xb, w1t, order,
                                     te2, tp2, tc2, te3, tp3, tc3);

    // dispatch 2: L1 256x256 GEMM (160) + W2T (512) + W3T (32) + reward (16)
    k_mix1<<<720, 512, 0, stream>>>(xb, w1t, b1, h1, order, te3, tp3, tc3,
                                    W2, w2t, W3, w3t);

    // dispatch 3: L2 256x256 GEMM (160 blocks)
    k_l2<<<160, 512, 0, stream>>>(h1, w2t, b2, h2, order, te3, tp3, tc3);

    // dispatch 4: L3 + fused reward (136 x 5 = 680 blocks of 64x64)
    k_l3<<<MAXT2 * 5, 256, 0, stream>>>(h2, w3t, b3, out, state, order,
                                        te2, tp2, tc2);
}